// Round 7
// baseline (256.989 us; speedup 1.0000x reference)
//
#include <hip/hip_runtime.h>
#include <stdint.h>

typedef unsigned short u16;
typedef unsigned int u32;
typedef __attribute__((ext_vector_type(8))) short short8;
typedef __attribute__((ext_vector_type(4))) float f32x4;
typedef __attribute__((ext_vector_type(4))) u16 u16x4;

#define DEV static __device__ __forceinline__

DEV void gload_lds16(const void* g, void* l) {
  __builtin_amdgcn_global_load_lds((const __attribute__((address_space(1))) void*)g,
                                   (__attribute__((address_space(3))) void*)l, 16, 0, 0);
}
DEV u16 f2bf(float x) {
  u32 u = __builtin_bit_cast(u32, x);
  return (u16)((u + 0x7fffu + ((u >> 16) & 1u)) >> 16);
}
DEV f32x4 mfma_bf16(short8 a, short8 b, f32x4 c) {
  return __builtin_amdgcn_mfma_f32_16x16x32_bf16(a, b, c, 0, 0, 0);
}

// ---------------------------------------------------------------------------
// f32 -> bf16 (RNE) conversion pre-pass over three concatenated arrays.
// ---------------------------------------------------------------------------
__global__ __launch_bounds__(256) void cvt3(
    const float* __restrict__ s0, u16* __restrict__ d0, int n0,
    const float* __restrict__ s1, u16* __restrict__ d1, int n1,
    const float* __restrict__ s2, u16* __restrict__ d2, int n2) {
  long i = (long)(blockIdx.x * 256 + threadIdx.x) * 4;
  const float* s; u16* d; long off;
  if (i < n0) { s = s0; d = d0; off = i; }
  else if (i < (long)n0 + n1) { s = s1; d = d1; off = i - n0; }
  else if (i < (long)n0 + n1 + n2) { s = s2; d = d2; off = i - n0 - n1; }
  else return;
  float4 v = *(const float4*)(s + off);
  u16x4 o; o.x = f2bf(v.x); o.y = f2bf(v.y); o.z = f2bf(v.z); o.w = f2bf(v.w);
  *(u16x4*)(d + off) = o;
}

// ---------------------------------------------------------------------------
// NT GEMM (unchanged from R4-passing): C = A·B^T + bias. M=8192, K=1024.
// ---------------------------------------------------------------------------
template <int MODE>
__global__ __launch_bounds__(256, 2) void gemm_nt(
    const u16* __restrict__ A, const u16* __restrict__ Bw,
    const float* __restrict__ bias, u16* __restrict__ O0, u16* __restrict__ O1,
    u16* __restrict__ O2, float* __restrict__ Of, int N, int K) {
  __shared__ __align__(16) u16 At[128 * 32];
  __shared__ __align__(16) u16 Bt[128 * 32];
  const int tid = threadIdx.x, w = tid >> 6, l = tid & 63;
  const int lr = l & 15, lg = l >> 4;
  const int m0 = blockIdx.y * 128, n0 = blockIdx.x * 128;
  const int wm = w >> 1, wn = w & 1;

  f32x4 acc[4][4];
#pragma unroll
  for (int i = 0; i < 4; i++)
#pragma unroll
    for (int j = 0; j < 4; j++) acc[i][j] = (f32x4){0.f, 0.f, 0.f, 0.f};

  for (int k0 = 0; k0 < K; k0 += 32) {
#pragma unroll
    for (int i = 0; i < 4; i++) {
      int seg = i * 4 + w;          // 0..15 ; <8 -> A, >=8 -> B
      int segl = seg & 7;
      int c = segl * 64 + l;        // 16B chunk 0..511
      int row = c >> 2, cpos = c & 3;
      int cdat = cpos ^ ((row >> 1) & 3);
      const u16* src = (seg < 8 ? A + (size_t)(m0 + row) * K
                                : Bw + (size_t)(n0 + row) * K) + (k0 + cdat * 8);
      u16* dst = (seg < 8 ? At : Bt) + segl * 512;
      gload_lds16(src, dst);
    }
    __syncthreads();

    short8 af[4], bf[4];
#pragma unroll
    for (int mi = 0; mi < 4; mi++) {
      int row = wm * 64 + mi * 16 + lr;
      int cp = lg ^ ((row >> 1) & 3);
      af[mi] = *(const short8*)&At[row * 32 + cp * 8];
    }
#pragma unroll
    for (int ni = 0; ni < 4; ni++) {
      int row = wn * 64 + ni * 16 + lr;
      int cp = lg ^ ((row >> 1) & 3);
      bf[ni] = *(const short8*)&Bt[row * 32 + cp * 8];
    }
#pragma unroll
    for (int mi = 0; mi < 4; mi++)
#pragma unroll
      for (int ni = 0; ni < 4; ni++)
        acc[mi][ni] = mfma_bf16(af[mi], bf[ni], acc[mi][ni]);
    __syncthreads();
  }

#pragma unroll
  for (int ni = 0; ni < 4; ni++) {
    int gn = n0 + wn * 64 + ni * 16 + lr;
    float bs = bias[gn];
#pragma unroll
    for (int mi = 0; mi < 4; mi++) {
#pragma unroll
      for (int r = 0; r < 4; r++) {
        int gm = m0 + wm * 64 + mi * 16 + lg * 4 + r;
        float val = acc[mi][ni][r] + bs;
        if (MODE == 0) {
          int which = gn >> 10, hd = gn & 1023;
          int h = hd >> 6, d = hd & 63;
          int b = gm >> 11, t = gm & 2047;
          u16* dst = which == 0 ? O0 : (which == 1 ? O1 : O2);
          dst[((size_t)(b * 16 + h) * 2048 + t) * 64 + d] = f2bf(val);
        } else {
          Of[(size_t)gm * N + gn] = val;
        }
      }
    }
  }
}

// ---------------------------------------------------------------------------
// Flash attention fwd — R7: 32 KB LDS -> 4 blocks/CU, all LDS XOR-swizzled
// conflict-free (col ^= (row&7)<<3, 8-u16 granularity). K and V reg-staged
// (T14 issue-early/write-late), single-buffered, 2 barriers/iter. Pl is
// wave-private (no barrier needed). Swapped QK^T + defer-max as R6-passing.
// ---------------------------------------------------------------------------
__global__ __launch_bounds__(256, 4) void attn_fwd(
    const u16* __restrict__ Q, const u16* __restrict__ Kg,
    const u16* __restrict__ Vg, u16* __restrict__ AO) {
  __shared__ __align__(16) u16 Kt[64 * 64];      // swizzled row-major [k][d]
  __shared__ __align__(16) u16 VT[64 * 64];      // swizzled transposed [d][t]
  __shared__ __align__(16) u16 Pl[4][32 * 64];   // swizzled per-wave [q][k]
  const int tid = threadIdx.x, w = tid >> 6, l = tid & 63;
  const int lr = l & 15, lg = l >> 4;
  const int bh = blockIdx.y;
  const int q0 = blockIdx.x * 128;
  const size_t base = (size_t)bh * 2048 * 64;
  const u16* Qb = Q + base;
  const u16* Kb = Kg + base;
  const u16* Vb = Vg + base;

  // K staging geometry: chunks c0,c1; row = c>>3 (tile-local), cpos = c&7.
  // LDS dst chunk = cpos ^ (row&7)  (same involution applied on read).
  const int c0 = w * 64 + l, c1 = (4 + w) * 64 + l;
  const int k0r = c0 >> 3, k0p = c0 & 7;
  const int k1r = c1 >> 3, k1p = c1 & 7;
  u16* kdst0 = &Kt[k0r * 64 + ((k0p ^ (k0r & 7)) << 3)];
  u16* kdst1 = &Kt[k1r * 64 + ((k1p ^ (k1r & 7)) << 3)];

  short8 qf[2][2];
#pragma unroll
  for (int qi = 0; qi < 2; qi++)
#pragma unroll
    for (int kk = 0; kk < 2; kk++)
      qf[qi][kk] = *(const short8*)&Qb[(size_t)(q0 + w * 32 + qi * 16 + lr) * 64 +
                                       kk * 32 + lg * 8];

  f32x4 oacc[2][4];
  float mrun[2], lrun[2];
#pragma unroll
  for (int qi = 0; qi < 2; qi++)
#pragma unroll
    for (int dj = 0; dj < 4; dj++) oacc[qi][dj] = (f32x4){0.f, 0.f, 0.f, 0.f};
  mrun[0] = mrun[1] = -3.0e38f;
  lrun[0] = lrun[1] = 0.f;

  // ---- prologue: load tile 0 into registers ----
  short8 kr0 = *(const short8*)(Kb + (size_t)k0r * 64 + k0p * 8);
  short8 kr1 = *(const short8*)(Kb + (size_t)k1r * 64 + k1p * 8);
  short8 vr0 = *(const short8*)(Vb + (size_t)l * 64 + w * 16);
  short8 vr1 = *(const short8*)(Vb + (size_t)l * 64 + w * 16 + 8);

  for (int kt = 0; kt < 32; kt++) {
    __syncthreads();  // A: previous iteration's Kt/VT reads complete
    // ---- write staged K (b128, swizzled) ----
    *(short8*)kdst0 = kr0;
    *(short8*)kdst1 = kr1;
    // ---- write staged V transposed (b16 scalar, swizzled cols) ----
#pragma unroll
    for (int e = 0; e < 8; e++) VT[(w * 16 + e) * 64 + (l ^ (e << 3))] = (u16)vr0[e];
#pragma unroll
    for (int e = 0; e < 8; e++) VT[(w * 16 + 8 + e) * 64 + (l ^ (e << 3))] = (u16)vr1[e];
    __syncthreads();  // B: publish Kt/VT

    // ---- issue next tile's global loads (consumed next iter after A) ----
    if (kt < 31) {
      const int t1 = (kt + 1) * 64;
      kr0 = *(const short8*)(Kb + (size_t)(t1 + k0r) * 64 + k0p * 8);
      kr1 = *(const short8*)(Kb + (size_t)(t1 + k1r) * 64 + k1p * 8);
      vr0 = *(const short8*)(Vb + (size_t)(t1 + l) * 64 + w * 16);
      vr1 = *(const short8*)(Vb + (size_t)(t1 + l) * 64 + w * 16 + 8);
    }

    // ---- S^T = K Q^T: st[qi][kj][r] = S[q=qi*16+lr][k=kj*16+lg*4+r] ----
    f32x4 st[2][4];
    __builtin_amdgcn_s_setprio(1);
#pragma unroll
    for (int kj = 0; kj < 4; kj++) {
      int row = kj * 16 + lr;
      const short8 kf0 = *(const short8*)&Kt[row * 64 + ((lg ^ (row & 7)) << 3)];
      const short8 kf1 = *(const short8*)&Kt[row * 64 + (((4 + lg) ^ (row & 7)) << 3)];
#pragma unroll
      for (int qi = 0; qi < 2; qi++) {
        f32x4 z = (f32x4){0.f, 0.f, 0.f, 0.f};
        z = mfma_bf16(kf0, qf[qi][0], z);
        z = mfma_bf16(kf1, qf[qi][1], z);
        st[qi][kj] = z;
      }
    }
    __builtin_amdgcn_s_setprio(0);

    // ---- tile max per q (in-register over k, then xor16/xor32) ----
    float pm[2];
#pragma unroll
    for (int qi = 0; qi < 2; qi++) {
      f32x4 m4;
#pragma unroll
      for (int r = 0; r < 4; r++)
        m4[r] = fmaxf(fmaxf(st[qi][0][r], st[qi][1][r]),
                      fmaxf(st[qi][2][r], st[qi][3][r]));
      float mx = fmaxf(fmaxf(m4[0], m4[1]), fmaxf(m4[2], m4[3]));
      mx = fmaxf(mx, __shfl_xor(mx, 16));
      mx = fmaxf(mx, __shfl_xor(mx, 32));
      pm[qi] = mx;
    }

    // ---- defer-max: rescale only when max grew by > 64 raw (8 post-scale) ----
    float lscale[2] = {1.f, 1.f};
    bool grow = (pm[0] > mrun[0] + 64.f) || (pm[1] > mrun[1] + 64.f);
    if (__any(grow)) {
#pragma unroll
      for (int qi = 0; qi < 2; qi++) {
        float mn = fmaxf(mrun[qi], pm[qi]);
        float e = __expf((mrun[qi] - mn) * 0.125f);
        mrun[qi] = mn;
        lscale[qi] = e;
        float er[4];
#pragma unroll
        for (int r = 0; r < 4; r++)
          er[r] = __shfl(e, (l & 48) | (lg * 4 + r));
#pragma unroll
        for (int dj = 0; dj < 4; dj++)
#pragma unroll
          for (int r = 0; r < 4; r++) oacc[qi][dj][r] *= er[r];
      }
    }

    // ---- P = exp((S - mrun)*scale); row-sum; write P b64 swizzled ----
#pragma unroll
    for (int qi = 0; qi < 2; qi++) {
#pragma unroll
      for (int kj = 0; kj < 4; kj++)
#pragma unroll
        for (int r = 0; r < 4; r++)
          st[qi][kj][r] = __expf((st[qi][kj][r] - mrun[qi]) * 0.125f);
      f32x4 s4 = st[qi][0];
#pragma unroll
      for (int kj = 1; kj < 4; kj++)
#pragma unroll
        for (int r = 0; r < 4; r++) s4[r] += st[qi][kj][r];
      float sv = (s4[0] + s4[1]) + (s4[2] + s4[3]);
      sv += __shfl_xor(sv, 16);
      sv += __shfl_xor(sv, 32);
      lrun[qi] = lrun[qi] * lscale[qi] + sv;
#pragma unroll
      for (int kj = 0; kj < 4; kj++) {
        u16x4 pk;
#pragma unroll
        for (int r = 0; r < 4; r++) pk[r] = f2bf(st[qi][kj][r]);
        *(u16x4*)&Pl[w][(qi * 16 + lr) * 64 +
                        ((kj * 16 + lg * 4) ^ ((lr & 7) << 3))] = pk;
      }
    }

    // ---- O += P V (b128 reads, swizzled; wave-private Pl needs no barrier) ----
#pragma unroll
    for (int kk = 0; kk < 2; kk++) {
      short8 pa[2], vb[4];
#pragma unroll
      for (int qi = 0; qi < 2; qi++)
        pa[qi] = *(const short8*)&Pl[w][(qi * 16 + lr) * 64 +
                                        ((kk * 32 + lg * 8) ^ ((lr & 7) << 3))];
#pragma unroll
      for (int dj = 0; dj < 4; dj++)
        vb[dj] = *(const short8*)&VT[(dj * 16 + lr) * 64 +
                                     ((kk * 32 + lg * 8) ^ ((lr & 7) << 3))];
      __builtin_amdgcn_s_setprio(1);
#pragma unroll
      for (int qi = 0; qi < 2; qi++)
#pragma unroll
        for (int dj = 0; dj < 4; dj++)
          oacc[qi][dj] = mfma_bf16(pa[qi], vb[dj], oacc[qi][dj]);
      __builtin_amdgcn_s_setprio(0);
    }
  }

  // ---- normalize (redistribute lrun from q=lr lanes to q=lg*4+r rows) ----
  const int b = bh >> 4, h = bh & 15;
#pragma unroll
  for (int qi = 0; qi < 2; qi++) {
    float inv[4];
#pragma unroll
    for (int r = 0; r < 4; r++) {
      float lv = __shfl(lrun[qi], (l & 48) | (lg * 4 + r));
      inv[r] = 1.0f / lv;
    }
#pragma unroll
    for (int dj = 0; dj < 4; dj++)
#pragma unroll
      for (int r = 0; r < 4; r++) {
        int t = q0 + w * 32 + qi * 16 + lg * 4 + r;
        AO[((size_t)(b * 2048 + t)) * 1024 + h * 64 + dj * 16 + lr] =
            f2bf(oacc[qi][dj][r] * inv[r]);
      }
  }
}

extern "C" void kernel_launch(void* const* d_in, const int* in_sizes, int n_in,
                              void* d_out, int out_size, void* d_ws,
                              size_t ws_size, hipStream_t stream) {
  const float* x    = (const float*)d_in[0];  // [4,2048,1024] f32
  const float* Wqkv = (const float*)d_in[1];  // [3072,1024] f32
  const float* bqkv = (const float*)d_in[2];  // [3072] f32
  const float* Wout = (const float*)d_in[3];  // [1024,1024] f32
  const float* bout = (const float*)d_in[4];  // [1024] f32
  float* out = (float*)d_out;                 // [4,2048,1024] f32

  u16* q     = (u16*)d_ws;
  u16* k     = q + (size_t)8388608;
  u16* v     = k + (size_t)8388608;
  u16* xb    = v + (size_t)8388608;
  u16* ao    = xb;  // alias: xb dead after gemm<0>
  u16* wqkvb = xb + (size_t)8388608;
  u16* woutb = wqkvb + (size_t)3145728;

  cvt3<<<12288, 256, 0, stream>>>(x, xb, 8388608, Wqkv, wqkvb, 3145728,
                                  Wout, woutb, 1048576);
  gemm_nt<0><<<dim3(24, 64), 256, 0, stream>>>(xb, wqkvb, bqkv, q, k, v,
                                               nullptr, 3072, 1024);
  attn_fwd<<<dim3(16, 64), 256, 0, stream>>>(q, k, v, ao);
  gemm_nt<1><<<dim3(8, 64), 256, 0, stream>>>(ao, woutb, bout, nullptr, nullptr,
                                              nullptr, out, 1024, 1024);
}

// Round 8
// 229.462 us; speedup vs baseline: 1.1200x; 1.1200x over previous
//
#include <hip/hip_runtime.h>
#include <stdint.h>

typedef unsigned short u16;
typedef unsigned int u32;
typedef __attribute__((ext_vector_type(8))) short short8;
typedef __attribute__((ext_vector_type(4))) float f32x4;
typedef __attribute__((ext_vector_type(4))) u16 u16x4;

#define DEV static __device__ __forceinline__

DEV void gload_lds16(const void* g, void* l) {
  __builtin_amdgcn_global_load_lds((const __attribute__((address_space(1))) void*)g,
                                   (__attribute__((address_space(3))) void*)l, 16, 0, 0);
}
DEV u16 f2bf(float x) {
  u32 u = __builtin_bit_cast(u32, x);
  return (u16)((u + 0x7fffu + ((u >> 16) & 1u)) >> 16);
}
DEV f32x4 mfma_bf16(short8 a, short8 b, f32x4 c) {
  return __builtin_amdgcn_mfma_f32_16x16x32_bf16(a, b, c, 0, 0, 0);
}

// ---------------------------------------------------------------------------
// f32 -> bf16 (RNE) conversion pre-pass over three concatenated arrays.
// ---------------------------------------------------------------------------
__global__ __launch_bounds__(256) void cvt3(
    const float* __restrict__ s0, u16* __restrict__ d0, int n0,
    const float* __restrict__ s1, u16* __restrict__ d1, int n1,
    const float* __restrict__ s2, u16* __restrict__ d2, int n2) {
  long i = (long)(blockIdx.x * 256 + threadIdx.x) * 4;
  const float* s; u16* d; long off;
  if (i < n0) { s = s0; d = d0; off = i; }
  else if (i < (long)n0 + n1) { s = s1; d = d1; off = i - n0; }
  else if (i < (long)n0 + n1 + n2) { s = s2; d = d2; off = i - n0 - n1; }
  else return;
  float4 v = *(const float4*)(s + off);
  u16x4 o; o.x = f2bf(v.x); o.y = f2bf(v.y); o.z = f2bf(v.z); o.w = f2bf(v.w);
  *(u16x4*)(d + off) = o;
}

// ---------------------------------------------------------------------------
// NT GEMM: C = A·B^T + bias. M=8192, K=1024. (R4-passing structure; MODE 0
// additionally folds the attention score scale 1/8 into Q — exact exponent
// shift, no rounding change.)
// ---------------------------------------------------------------------------
template <int MODE>
__global__ __launch_bounds__(256, 2) void gemm_nt(
    const u16* __restrict__ A, const u16* __restrict__ Bw,
    const float* __restrict__ bias, u16* __restrict__ O0, u16* __restrict__ O1,
    u16* __restrict__ O2, float* __restrict__ Of, int N, int K) {
  __shared__ __align__(16) u16 At[128 * 32];
  __shared__ __align__(16) u16 Bt[128 * 32];
  const int tid = threadIdx.x, w = tid >> 6, l = tid & 63;
  const int lr = l & 15, lg = l >> 4;
  const int m0 = blockIdx.y * 128, n0 = blockIdx.x * 128;
  const int wm = w >> 1, wn = w & 1;

  f32x4 acc[4][4];
#pragma unroll
  for (int i = 0; i < 4; i++)
#pragma unroll
    for (int j = 0; j < 4; j++) acc[i][j] = (f32x4){0.f, 0.f, 0.f, 0.f};

  for (int k0 = 0; k0 < K; k0 += 32) {
#pragma unroll
    for (int i = 0; i < 4; i++) {
      int seg = i * 4 + w;          // 0..15 ; <8 -> A, >=8 -> B
      int segl = seg & 7;
      int c = segl * 64 + l;        // 16B chunk 0..511
      int row = c >> 2, cpos = c & 3;
      int cdat = cpos ^ ((row >> 1) & 3);
      const u16* src = (seg < 8 ? A + (size_t)(m0 + row) * K
                                : Bw + (size_t)(n0 + row) * K) + (k0 + cdat * 8);
      u16* dst = (seg < 8 ? At : Bt) + segl * 512;
      gload_lds16(src, dst);
    }
    __syncthreads();

    short8 af[4], bf[4];
#pragma unroll
    for (int mi = 0; mi < 4; mi++) {
      int row = wm * 64 + mi * 16 + lr;
      int cp = lg ^ ((row >> 1) & 3);
      af[mi] = *(const short8*)&At[row * 32 + cp * 8];
    }
#pragma unroll
    for (int ni = 0; ni < 4; ni++) {
      int row = wn * 64 + ni * 16 + lr;
      int cp = lg ^ ((row >> 1) & 3);
      bf[ni] = *(const short8*)&Bt[row * 32 + cp * 8];
    }
#pragma unroll
    for (int mi = 0; mi < 4; mi++)
#pragma unroll
      for (int ni = 0; ni < 4; ni++)
        acc[mi][ni] = mfma_bf16(af[mi], bf[ni], acc[mi][ni]);
    __syncthreads();
  }

#pragma unroll
  for (int ni = 0; ni < 4; ni++) {
    int gn = n0 + wn * 64 + ni * 16 + lr;
    float bs = bias[gn];
#pragma unroll
    for (int mi = 0; mi < 4; mi++) {
#pragma unroll
      for (int r = 0; r < 4; r++) {
        int gm = m0 + wm * 64 + mi * 16 + lg * 4 + r;
        float val = acc[mi][ni][r] + bs;
        if (MODE == 0) {
          int which = gn >> 10, hd = gn & 1023;
          int h = hd >> 6, d = hd & 63;
          int b = gm >> 11, t = gm & 2047;
          if (which == 0) val *= 0.125f;  // fold 1/sqrt(Dh) into Q (exact)
          u16* dst = which == 0 ? O0 : (which == 1 ? O1 : O2);
          dst[((size_t)(b * 16 + h) * 2048 + t) * 64 + d] = f2bf(val);
        } else {
          Of[(size_t)gm * N + gn] = val;
        }
      }
    }
  }
}

// ---------------------------------------------------------------------------
// Flash attention fwd — R8: R6-passing structure (K global_load_lds dbuf +
// V reg-staged write-late dbuf, ONE barrier/iter, swapped QK^T, defer-max)
// + R7-proven XOR swizzles on VT/Pl (unpadded, 48 KB -> 3 blocks/CU)
// + XCD-aware block->bh pinning (all 16 q-tiles of a bh on one XCD).
// Q is pre-scaled by 1/8 in gemm<0>, so scores are final (THR=8).
// ---------------------------------------------------------------------------
__global__ __launch_bounds__(256, 3) void attn_fwd(
    const u16* __restrict__ Q, const u16* __restrict__ Kg,
    const u16* __restrict__ Vg, u16* __restrict__ AO) {
  __shared__ __align__(16) u16 Kt[2][64 * 64];   // src-swizzled via gload_lds
  __shared__ __align__(16) u16 VT[2][64 * 64];   // [d][t], col ^= (row&7)<<3
  __shared__ __align__(16) u16 Pl[4][32 * 64];   // [q][k], col ^= (lr&7)<<3
  const int tid = threadIdx.x, w = tid >> 6, l = tid & 63;
  const int lr = l & 15, lg = l >> 4;
  // XCD-aware remap: round-robin HW assignment (wgid%8) -> pin bh to XCD.
  const int wgid = blockIdx.x;
  const int xcd = wgid & 7, slot = wgid >> 3;
  const int bh = xcd * 8 + (slot >> 4);
  const int q0 = (slot & 15) * 128;
  const size_t base = (size_t)bh * 2048 * 64;
  const u16* Qb = Q + base;
  const u16* Kb = Kg + base;
  const u16* Vb = Vg + base;

  short8 qf[2][2];
#pragma unroll
  for (int qi = 0; qi < 2; qi++)
#pragma unroll
    for (int kk = 0; kk < 2; kk++)
      qf[qi][kk] = *(const short8*)&Qb[(size_t)(q0 + w * 32 + qi * 16 + lr) * 64 +
                                       kk * 32 + lg * 8];

  f32x4 oacc[2][4];
  float mrun[2], lrun[2];
#pragma unroll
  for (int qi = 0; qi < 2; qi++)
#pragma unroll
    for (int dj = 0; dj < 4; dj++) oacc[qi][dj] = (f32x4){0.f, 0.f, 0.f, 0.f};
  mrun[0] = mrun[1] = -3.0e38f;
  lrun[0] = lrun[1] = 0.f;

  // ---- prologue: stage tile 0 into buffer 0 ----
  {
#pragma unroll
    for (int i = 0; i < 2; i++) {
      int seg = i * 4 + w;
      int c = seg * 64 + l;
      int row = c >> 3, cpos = c & 7, cdat = cpos ^ (row & 7);
      gload_lds16(Kb + (size_t)row * 64 + cdat * 8, (u16*)&Kt[0][0] + seg * 512);
    }
    const u16* vsrc = &Vb[(size_t)l * 64 + w * 16];
    short8 v0 = *(const short8*)vsrc;
    short8 v1 = *(const short8*)(vsrc + 8);
#pragma unroll
    for (int e = 0; e < 8; e++)
      VT[0][(w * 16 + e) * 64 + (l ^ (e << 3))] = (u16)v0[e];
#pragma unroll
    for (int e = 0; e < 8; e++)
      VT[0][(w * 16 + 8 + e) * 64 + (l ^ (e << 3))] = (u16)v1[e];
  }
  __syncthreads();

  for (int kt = 0; kt < 32; kt++) {
    const int cur = kt & 1, nxt = cur ^ 1;
    short8 vr0, vr1;
    const bool pf = (kt < 31);
    if (pf) {
      const int t1 = (kt + 1) * 64;
      // K prefetch direct-to-LDS (inactive buffer)
#pragma unroll
      for (int i = 0; i < 2; i++) {
        int seg = i * 4 + w;
        int c = seg * 64 + l;
        int row = c >> 3, cpos = c & 7, cdat = cpos ^ (row & 7);
        gload_lds16(Kb + (size_t)(t1 + row) * 64 + cdat * 8,
                    (u16*)&Kt[nxt][0] + seg * 512);
      }
      // V prefetch to registers (LDS write deferred past softmax)
      const u16* vsrc = &Vb[(size_t)(t1 + l) * 64 + w * 16];
      vr0 = *(const short8*)vsrc;
      vr1 = *(const short8*)(vsrc + 8);
    }

    // ---- S^T = K Q^T: st[qi][kj][r] = S[q=qi*16+lr][k=kj*16+lg*4+r] ----
    f32x4 st[2][4];
    __builtin_amdgcn_s_setprio(1);
#pragma unroll
    for (int kj = 0; kj < 4; kj++) {
      int row = kj * 16 + lr;
      const short8 kf0 = *(const short8*)&Kt[cur][row * 64 + ((lg ^ (row & 7)) << 3)];
      const short8 kf1 = *(const short8*)&Kt[cur][row * 64 + (((4 + lg) ^ (row & 7)) << 3)];
#pragma unroll
      for (int qi = 0; qi < 2; qi++) {
        f32x4 z = (f32x4){0.f, 0.f, 0.f, 0.f};
        z = mfma_bf16(kf0, qf[qi][0], z);
        z = mfma_bf16(kf1, qf[qi][1], z);
        st[qi][kj] = z;
      }
    }
    __builtin_amdgcn_s_setprio(0);

    // ---- tile max per q (in-register over k, then xor16/xor32) ----
    float pm[2];
#pragma unroll
    for (int qi = 0; qi < 2; qi++) {
      f32x4 m4;
#pragma unroll
      for (int r = 0; r < 4; r++)
        m4[r] = fmaxf(fmaxf(st[qi][0][r], st[qi][1][r]),
                      fmaxf(st[qi][2][r], st[qi][3][r]));
      float mx = fmaxf(fmaxf(m4[0], m4[1]), fmaxf(m4[2], m4[3]));
      mx = fmaxf(mx, __shfl_xor(mx, 16));
      mx = fmaxf(mx, __shfl_xor(mx, 32));
      pm[qi] = mx;
    }

    // ---- defer-max: rescale only when max grew by > 8 (scores pre-scaled) ----
    float lscale[2] = {1.f, 1.f};
    bool grow = (pm[0] > mrun[0] + 8.f) || (pm[1] > mrun[1] + 8.f);
    if (__any(grow)) {
#pragma unroll
      for (int qi = 0; qi < 2; qi++) {
        float mn = fmaxf(mrun[qi], pm[qi]);
        float e = __expf(mrun[qi] - mn);
        mrun[qi] = mn;
        lscale[qi] = e;
        float er[4];
#pragma unroll
        for (int r = 0; r < 4; r++)
          er[r] = __shfl(e, (l & 48) | (lg * 4 + r));
#pragma unroll
        for (int dj = 0; dj < 4; dj++)
#pragma unroll
          for (int r = 0; r < 4; r++) oacc[qi][dj][r] *= er[r];
      }
    }

    // ---- P = exp(S - mrun); row-sum; write P b64 swizzled ----
#pragma unroll
    for (int qi = 0; qi < 2; qi++) {
#pragma unroll
      for (int kj = 0; kj < 4; kj++)
#pragma unroll
        for (int r = 0; r < 4; r++)
          st[qi][kj][r] = __expf(st[qi][kj][r] - mrun[qi]);
      f32x4 s4 = st[qi][0];
#pragma unroll
      for (int kj = 1; kj < 4; kj++)
#pragma unroll
        for (int r = 0; r < 4; r++) s4[r] += st[qi][kj][r];
      float sv = (s4[0] + s4[1]) + (s4[2] + s4[3]);
      sv += __shfl_xor(sv, 16);
      sv += __shfl_xor(sv, 32);
      lrun[qi] = lrun[qi] * lscale[qi] + sv;
#pragma unroll
      for (int kj = 0; kj < 4; kj++) {
        u16x4 pk;
#pragma unroll
        for (int r = 0; r < 4; r++) pk[r] = f2bf(st[qi][kj][r]);
        *(u16x4*)&Pl[w][(qi * 16 + lr) * 64 +
                        ((kj * 16 + lg * 4) ^ ((lr & 7) << 3))] = pk;
      }
    }

    // ---- write prefetched V into inactive VT buffer (loads have aged) ----
    if (pf) {
#pragma unroll
      for (int e = 0; e < 8; e++)
        VT[nxt][(w * 16 + e) * 64 + (l ^ (e << 3))] = (u16)vr0[e];
#pragma unroll
      for (int e = 0; e < 8; e++)
        VT[nxt][(w * 16 + 8 + e) * 64 + (l ^ (e << 3))] = (u16)vr1[e];
    }

    // ---- O += P V (b128 swizzled reads; Pl wave-private, no barrier) ----
#pragma unroll
    for (int kk = 0; kk < 2; kk++) {
      short8 pa[2], vb[4];
#pragma unroll
      for (int qi = 0; qi < 2; qi++)
        pa[qi] = *(const short8*)&Pl[w][(qi * 16 + lr) * 64 +
                                        ((kk * 32 + lg * 8) ^ ((lr & 7) << 3))];
#pragma unroll
      for (int dj = 0; dj < 4; dj++)
        vb[dj] = *(const short8*)&VT[cur][(dj * 16 + lr) * 64 +
                                          ((kk * 32 + lg * 8) ^ ((lr & 7) << 3))];
      __builtin_amdgcn_s_setprio(1);
#pragma unroll
      for (int qi = 0; qi < 2; qi++)
#pragma unroll
        for (int dj = 0; dj < 4; dj++)
          oacc[qi][dj] = mfma_bf16(pa[qi], vb[dj], oacc[qi][dj]);
      __builtin_amdgcn_s_setprio(0);
    }
    // single barrier: ends this tile's Kt/VT reads and (via its implicit
    // vmcnt/lgkm drain) publishes Kt[nxt]/VT[nxt] for the next iteration.
    __syncthreads();
  }

  // ---- normalize (redistribute lrun from q=lr lanes to q=lg*4+r rows) ----
  const int b = bh >> 4, h = bh & 15;
#pragma unroll
  for (int qi = 0; qi < 2; qi++) {
    float inv[4];
#pragma unroll
    for (int r = 0; r < 4; r++) {
      float lv = __shfl(lrun[qi], (l & 48) | (lg * 4 + r));
      inv[r] = 1.0f / lv;
    }
#pragma unroll
    for (int dj = 0; dj < 4; dj++)
#pragma unroll
      for (int r = 0; r < 4; r++) {
        int t = q0 + w * 32 + qi * 16 + lg * 4 + r;
        AO[((size_t)(b * 2048 + t)) * 1024 + h * 64 + dj * 16 + lr] =
            f2bf(oacc[qi][dj][r] * inv[r]);
      }
  }
}

extern "C" void kernel_launch(void* const* d_in, const int* in_sizes, int n_in,
                              void* d_out, int out_size, void* d_ws,
                              size_t ws_size, hipStream_t stream) {
  const float* x    = (const float*)d_in[0];  // [4,2048,1024] f32
  const float* Wqkv = (const float*)d_in[1];  // [3072,1024] f32
  const float* bqkv = (const float*)d_in[2];  // [3072] f32
  const float* Wout = (const float*)d_in[3];  // [1024,1024] f32
  const float* bout = (const float*)d_in[4];  // [1024] f32
  float* out = (float*)d_out;                 // [4,2048,1024] f32

  u16* q     = (u16*)d_ws;
  u16* k     = q + (size_t)8388608;
  u16* v     = k + (size_t)8388608;
  u16* xb    = v + (size_t)8388608;
  u16* ao    = xb;  // alias: xb dead after gemm<0>
  u16* wqkvb = xb + (size_t)8388608;
  u16* woutb = wqkvb + (size_t)3145728;

  cvt3<<<12288, 256, 0, stream>>>(x, xb, 8388608, Wqkv, wqkvb, 3145728,
                                  Wout, woutb, 1048576);
  gemm_nt<0><<<dim3(24, 64), 256, 0, stream>>>(xb, wqkvb, bqkv, q, k, v,
                                               nullptr, 3072, 1024);
  attn_fwd<<<1024, 256, 0, stream>>>(q, k, v, ao);
  gemm_nt<1><<<dim3(8, 64), 256, 0, stream>>>(ao, woutb, bout, nullptr, nullptr,
                                              nullptr, out, 1024, 1024);
}

// Round 9
// 227.669 us; speedup vs baseline: 1.1288x; 1.0079x over previous
//
#include <hip/hip_runtime.h>
#include <hip/hip_bf16.h>
#include <stdint.h>

typedef unsigned short u16;
typedef unsigned int u32;
typedef __attribute__((ext_vector_type(8))) short short8;
typedef __attribute__((ext_vector_type(4))) float f32x4;
typedef __attribute__((ext_vector_type(4))) u16 u16x4;

#define DEV static __device__ __forceinline__

DEV void gload_lds16(const void* g, void* l) {
  __builtin_amdgcn_global_load_lds((const __attribute__((address_space(1))) void*)g,
                                   (__attribute__((address_space(3))) void*)l, 16, 0, 0);
}
DEV u16 f2bf(float x) {
  u32 u = __builtin_bit_cast(u32, x);
  return (u16)((u + 0x7fffu + ((u >> 16) & 1u)) >> 16);
}
DEV u16 f2bfn(float x) {  // native RNE cvt (compiler emits v_cvt_pk_bf16_f32)
  __hip_bfloat16 h = __float2bfloat16(x);
  return __builtin_bit_cast(u16, h);
}
DEV f32x4 mfma_bf16(short8 a, short8 b, f32x4 c) {
  return __builtin_amdgcn_mfma_f32_16x16x32_bf16(a, b, c, 0, 0, 0);
}

// ---------------------------------------------------------------------------
// f32 -> bf16 (RNE) conversion pre-pass over three concatenated arrays.
// ---------------------------------------------------------------------------
__global__ __launch_bounds__(256) void cvt3(
    const float* __restrict__ s0, u16* __restrict__ d0, int n0,
    const float* __restrict__ s1, u16* __restrict__ d1, int n1,
    const float* __restrict__ s2, u16* __restrict__ d2, int n2) {
  long i = (long)(blockIdx.x * 256 + threadIdx.x) * 4;
  const float* s; u16* d; long off;
  if (i < n0) { s = s0; d = d0; off = i; }
  else if (i < (long)n0 + n1) { s = s1; d = d1; off = i - n0; }
  else if (i < (long)n0 + n1 + n2) { s = s2; d = d2; off = i - n0 - n1; }
  else return;
  float4 v = *(const float4*)(s + off);
  u16x4 o; o.x = f2bf(v.x); o.y = f2bf(v.y); o.z = f2bf(v.z); o.w = f2bf(v.w);
  *(u16x4*)(d + off) = o;
}

// ---------------------------------------------------------------------------
// V transpose: v [64 bh][2048 t][64 d] -> vt [64 bh][64 d][2048 t].
// Thread handles 2 consecutive t rows; stores u32 pairs, wave-coalesced.
// ---------------------------------------------------------------------------
__global__ __launch_bounds__(256) void transposeV(
    const u16* __restrict__ v, u16* __restrict__ vt) {
  const int bh = blockIdx.y, chunk = blockIdx.x, tid = threadIdx.x;
  const int t0 = chunk * 512 + tid * 2;
  const u16* src = v + (size_t)bh * 131072 + (size_t)t0 * 64;
  u16* dst = vt + (size_t)bh * 131072 + t0;
  short8 a[8], b[8];
#pragma unroll
  for (int j = 0; j < 8; j++) {
    a[j] = *(const short8*)(src + j * 8);
    b[j] = *(const short8*)(src + 64 + j * 8);
  }
#pragma unroll
  for (int j = 0; j < 8; j++)
#pragma unroll
    for (int e = 0; e < 8; e++) {
      int d = j * 8 + e;
      u32 pk = (u32)(u16)a[j][e] | ((u32)(u16)b[j][e] << 16);
      *(u32*)(dst + (size_t)d * 2048) = pk;
    }
}

// ---------------------------------------------------------------------------
// NT GEMM: C = A·B^T + bias. M=8192, K=1024. (unchanged R8-passing; MODE 0
// folds the attention score scale 1/8 into Q — exact exponent shift.)
// ---------------------------------------------------------------------------
template <int MODE>
__global__ __launch_bounds__(256, 2) void gemm_nt(
    const u16* __restrict__ A, const u16* __restrict__ Bw,
    const float* __restrict__ bias, u16* __restrict__ O0, u16* __restrict__ O1,
    u16* __restrict__ O2, float* __restrict__ Of, int N, int K) {
  __shared__ __align__(16) u16 At[128 * 32];
  __shared__ __align__(16) u16 Bt[128 * 32];
  const int tid = threadIdx.x, w = tid >> 6, l = tid & 63;
  const int lr = l & 15, lg = l >> 4;
  const int m0 = blockIdx.y * 128, n0 = blockIdx.x * 128;
  const int wm = w >> 1, wn = w & 1;

  f32x4 acc[4][4];
#pragma unroll
  for (int i = 0; i < 4; i++)
#pragma unroll
    for (int j = 0; j < 4; j++) acc[i][j] = (f32x4){0.f, 0.f, 0.f, 0.f};

  for (int k0 = 0; k0 < K; k0 += 32) {
#pragma unroll
    for (int i = 0; i < 4; i++) {
      int seg = i * 4 + w;          // 0..15 ; <8 -> A, >=8 -> B
      int segl = seg & 7;
      int c = segl * 64 + l;        // 16B chunk 0..511
      int row = c >> 2, cpos = c & 3;
      int cdat = cpos ^ ((row >> 1) & 3);
      const u16* src = (seg < 8 ? A + (size_t)(m0 + row) * K
                                : Bw + (size_t)(n0 + row) * K) + (k0 + cdat * 8);
      u16* dst = (seg < 8 ? At : Bt) + segl * 512;
      gload_lds16(src, dst);
    }
    __syncthreads();

    short8 af[4], bf[4];
#pragma unroll
    for (int mi = 0; mi < 4; mi++) {
      int row = wm * 64 + mi * 16 + lr;
      int cp = lg ^ ((row >> 1) & 3);
      af[mi] = *(const short8*)&At[row * 32 + cp * 8];
    }
#pragma unroll
    for (int ni = 0; ni < 4; ni++) {
      int row = wn * 64 + ni * 16 + lr;
      int cp = lg ^ ((row >> 1) & 3);
      bf[ni] = *(const short8*)&Bt[row * 32 + cp * 8];
    }
#pragma unroll
    for (int mi = 0; mi < 4; mi++)
#pragma unroll
      for (int ni = 0; ni < 4; ni++)
        acc[mi][ni] = mfma_bf16(af[mi], bf[ni], acc[mi][ni]);
    __syncthreads();
  }

#pragma unroll
  for (int ni = 0; ni < 4; ni++) {
    int gn = n0 + wn * 64 + ni * 16 + lr;
    float bs = bias[gn];
#pragma unroll
    for (int mi = 0; mi < 4; mi++) {
#pragma unroll
      for (int r = 0; r < 4; r++) {
        int gm = m0 + wm * 64 + mi * 16 + lg * 4 + r;
        float val = acc[mi][ni][r] + bs;
        if (MODE == 0) {
          int which = gn >> 10, hd = gn & 1023;
          int h = hd >> 6, d = hd & 63;
          int b = gm >> 11, t = gm & 2047;
          if (which == 0) val *= 0.125f;  // fold 1/sqrt(Dh) into Q (exact)
          u16* dst = which == 0 ? O0 : (which == 1 ? O1 : O2);
          dst[((size_t)(b * 16 + h) * 2048 + t) * 64 + d] = f2bf(val);
        } else {
          Of[(size_t)gm * N + gn] = val;
        }
      }
    }
  }
}

// ---------------------------------------------------------------------------
// Flash attention fwd — R9: BOTH K and V^T staged via global_load_lds
// (double-buffered, source-XOR-swizzled), V pre-transposed globally. No
// reg-staged transpose in the loop; native bf16 cvt for P. One barrier/iter,
// swapped QK^T, defer-max, XCD-pinned bh. Q pre-scaled by 1/8.
// ---------------------------------------------------------------------------
__global__ __launch_bounds__(256, 3) void attn_fwd(
    const u16* __restrict__ Q, const u16* __restrict__ Kg,
    const u16* __restrict__ VTg, u16* __restrict__ AO) {
  __shared__ __align__(16) u16 Kt[2][64 * 64];   // [k][d], src-swizzled
  __shared__ __align__(16) u16 VT[2][64 * 64];   // [d][t], src-swizzled
  __shared__ __align__(16) u16 Pl[4][32 * 64];   // [q][k], col ^= (lr&7)<<3
  const int tid = threadIdx.x, w = tid >> 6, l = tid & 63;
  const int lr = l & 15, lg = l >> 4;
  const int wgid = blockIdx.x;
  const int xcd = wgid & 7, slot = wgid >> 3;
  const int bh = xcd * 8 + (slot >> 4);
  const int q0 = (slot & 15) * 128;
  const size_t base = (size_t)bh * 2048 * 64;
  const u16* Qb = Q + base;
  const u16* Kb = Kg + base;
  const u16* VTb = VTg + base;   // [64 d][2048 t]

  short8 qf[2][2];
#pragma unroll
  for (int qi = 0; qi < 2; qi++)
#pragma unroll
    for (int kk = 0; kk < 2; kk++)
      qf[qi][kk] = *(const short8*)&Qb[(size_t)(q0 + w * 32 + qi * 16 + lr) * 64 +
                                       kk * 32 + lg * 8];

  f32x4 oacc[2][4];
  float mrun[2], lrun[2];
#pragma unroll
  for (int qi = 0; qi < 2; qi++)
#pragma unroll
    for (int dj = 0; dj < 4; dj++) oacc[qi][dj] = (f32x4){0.f, 0.f, 0.f, 0.f};
  mrun[0] = mrun[1] = -3.0e38f;
  lrun[0] = lrun[1] = 0.f;

  // staging geometry (shared by K and VT): seg = i*4+w, c = seg*64+l
  // K:  row=c>>3 (k), cdat=(c&7)^(row&7), src = Kb  + (t0+row)*64 + cdat*8
  // VT: row=c>>3 (d), cdat=(c&7)^(row&7), src = VTb + row*2048 + t0 + cdat*8
  // ---- prologue: stage tile 0 into buffer 0 ----
  {
#pragma unroll
    for (int i = 0; i < 2; i++) {
      int seg = i * 4 + w;
      int c = seg * 64 + l;
      int row = c >> 3, cdat = (c & 7) ^ (row & 7);
      gload_lds16(Kb + (size_t)row * 64 + cdat * 8, (u16*)&Kt[0][0] + seg * 512);
      gload_lds16(VTb + (size_t)row * 2048 + cdat * 8, (u16*)&VT[0][0] + seg * 512);
    }
  }
  __syncthreads();

  for (int kt = 0; kt < 32; kt++) {
    const int cur = kt & 1, nxt = cur ^ 1;
    if (kt < 31) {
      const int t1 = (kt + 1) * 64;
#pragma unroll
      for (int i = 0; i < 2; i++) {
        int seg = i * 4 + w;
        int c = seg * 64 + l;
        int row = c >> 3, cdat = (c & 7) ^ (row & 7);
        gload_lds16(Kb + (size_t)(t1 + row) * 64 + cdat * 8,
                    (u16*)&Kt[nxt][0] + seg * 512);
        gload_lds16(VTb + (size_t)row * 2048 + t1 + cdat * 8,
                    (u16*)&VT[nxt][0] + seg * 512);
      }
    }

    // ---- S^T = K Q^T: st[qi][kj][r] = S[q=qi*16+lr][k=kj*16+lg*4+r] ----
    f32x4 st[2][4];
    __builtin_amdgcn_s_setprio(1);
#pragma unroll
    for (int kj = 0; kj < 4; kj++) {
      int row = kj * 16 + lr;
      const short8 kf0 = *(const short8*)&Kt[cur][row * 64 + ((lg ^ (row & 7)) << 3)];
      const short8 kf1 = *(const short8*)&Kt[cur][row * 64 + (((4 + lg) ^ (row & 7)) << 3)];
#pragma unroll
      for (int qi = 0; qi < 2; qi++) {
        f32x4 z = (f32x4){0.f, 0.f, 0.f, 0.f};
        z = mfma_bf16(kf0, qf[qi][0], z);
        z = mfma_bf16(kf1, qf[qi][1], z);
        st[qi][kj] = z;
      }
    }
    __builtin_amdgcn_s_setprio(0);

    // ---- tile max per q (in-register over k, then xor16/xor32) ----
    float pm[2];
#pragma unroll
    for (int qi = 0; qi < 2; qi++) {
      f32x4 m4;
#pragma unroll
      for (int r = 0; r < 4; r++)
        m4[r] = fmaxf(fmaxf(st[qi][0][r], st[qi][1][r]),
                      fmaxf(st[qi][2][r], st[qi][3][r]));
      float mx = fmaxf(fmaxf(m4[0], m4[1]), fmaxf(m4[2], m4[3]));
      mx = fmaxf(mx, __shfl_xor(mx, 16));
      mx = fmaxf(mx, __shfl_xor(mx, 32));
      pm[qi] = mx;
    }

    // ---- defer-max: rescale only when max grew by > 8 ----
    float lscale[2] = {1.f, 1.f};
    bool grow = (pm[0] > mrun[0] + 8.f) || (pm[1] > mrun[1] + 8.f);
    if (__any(grow)) {
#pragma unroll
      for (int qi = 0; qi < 2; qi++) {
        float mn = fmaxf(mrun[qi], pm[qi]);
        float e = __expf(mrun[qi] - mn);
        mrun[qi] = mn;
        lscale[qi] = e;
        float er[4];
#pragma unroll
        for (int r = 0; r < 4; r++)
          er[r] = __shfl(e, (l & 48) | (lg * 4 + r));
#pragma unroll
        for (int dj = 0; dj < 4; dj++)
#pragma unroll
          for (int r = 0; r < 4; r++) oacc[qi][dj][r] *= er[r];
      }
    }

    // ---- P = exp(S - mrun); row-sum; write P b64 swizzled ----
#pragma unroll
    for (int qi = 0; qi < 2; qi++) {
#pragma unroll
      for (int kj = 0; kj < 4; kj++)
#pragma unroll
        for (int r = 0; r < 4; r++)
          st[qi][kj][r] = __expf(st[qi][kj][r] - mrun[qi]);
      f32x4 s4 = st[qi][0];
#pragma unroll
      for (int kj = 1; kj < 4; kj++)
#pragma unroll
        for (int r = 0; r < 4; r++) s4[r] += st[qi][kj][r];
      float sv = (s4[0] + s4[1]) + (s4[2] + s4[3]);
      sv += __shfl_xor(sv, 16);
      sv += __shfl_xor(sv, 32);
      lrun[qi] = lrun[qi] * lscale[qi] + sv;
#pragma unroll
      for (int kj = 0; kj < 4; kj++) {
        u16x4 pk;
#pragma unroll
        for (int r = 0; r < 4; r++) pk[r] = f2bfn(st[qi][kj][r]);
        *(u16x4*)&Pl[w][(qi * 16 + lr) * 64 +
                        ((kj * 16 + lg * 4) ^ ((lr & 7) << 3))] = pk;
      }
    }

    // ---- O += P V (b128 swizzled reads; Pl wave-private, no barrier) ----
#pragma unroll
    for (int kk = 0; kk < 2; kk++) {
      short8 pa[2], vb[4];
#pragma unroll
      for (int qi = 0; qi < 2; qi++)
        pa[qi] = *(const short8*)&Pl[w][(qi * 16 + lr) * 64 +
                                        ((kk * 32 + lg * 8) ^ ((lr & 7) << 3))];
#pragma unroll
      for (int dj = 0; dj < 4; dj++)
        vb[dj] = *(const short8*)&VT[cur][(dj * 16 + lr) * 64 +
                                          ((kk * 32 + lg * 8) ^ ((lr & 7) << 3))];
      __builtin_amdgcn_s_setprio(1);
#pragma unroll
      for (int qi = 0; qi < 2; qi++)
#pragma unroll
        for (int dj = 0; dj < 4; dj++)
          oacc[qi][dj] = mfma_bf16(pa[qi], vb[dj], oacc[qi][dj]);
      __builtin_amdgcn_s_setprio(0);
    }
    // single barrier: ends this tile's Kt/VT reads; its implicit vmcnt/lgkm
    // drain publishes Kt[nxt]/VT[nxt] for the next iteration.
    __syncthreads();
  }

  // ---- normalize (redistribute lrun from q=lr lanes to q=lg*4+r rows) ----
  const int b = bh >> 4, h = bh & 15;
#pragma unroll
  for (int qi = 0; qi < 2; qi++) {
    float inv[4];
#pragma unroll
    for (int r = 0; r < 4; r++) {
      float lv = __shfl(lrun[qi], (l & 48) | (lg * 4 + r));
      inv[r] = 1.0f / lv;
    }
#pragma unroll
    for (int dj = 0; dj < 4; dj++)
#pragma unroll
      for (int r = 0; r < 4; r++) {
        int t = q0 + w * 32 + qi * 16 + lg * 4 + r;
        AO[((size_t)(b * 2048 + t)) * 1024 + h * 64 + dj * 16 + lr] =
            f2bfn(oacc[qi][dj][r] * inv[r]);
      }
  }
}

extern "C" void kernel_launch(void* const* d_in, const int* in_sizes, int n_in,
                              void* d_out, int out_size, void* d_ws,
                              size_t ws_size, hipStream_t stream) {
  const float* x    = (const float*)d_in[0];  // [4,2048,1024] f32
  const float* Wqkv = (const float*)d_in[1];  // [3072,1024] f32
  const float* bqkv = (const float*)d_in[2];  // [3072] f32
  const float* Wout = (const float*)d_in[3];  // [1024,1024] f32
  const float* bout = (const float*)d_in[4];  // [1024] f32
  float* out = (float*)d_out;                 // [4,2048,1024] f32

  u16* q     = (u16*)d_ws;
  u16* k     = q + (size_t)8388608;
  u16* v     = k + (size_t)8388608;
  u16* xb    = v + (size_t)8388608;
  u16* wqkvb = xb + (size_t)8388608;
  u16* woutb = wqkvb + (size_t)3145728;
  u16* vt    = xb;  // alias: xb dead after gemm<0>
  u16* ao    = v;   // alias: v dead after transposeV

  cvt3<<<12288, 256, 0, stream>>>(x, xb, 8388608, Wqkv, wqkvb, 3145728,
                                  Wout, woutb, 1048576);
  gemm_nt<0><<<dim3(24, 64), 256, 0, stream>>>(xb, wqkvb, bqkv, q, k, v,
                                               nullptr, 3072, 1024);
  transposeV<<<dim3(4, 64), 256, 0, stream>>>(v, vt);
  attn_fwd<<<1024, 256, 0, stream>>>(q, k, vt, ao);
  gemm_nt<1><<<dim3(8, 64), 256, 0, stream>>>(ao, woutb, bout, nullptr, nullptr,
                                              nullptr, out, 1024, 1024);
}